// Round 4
// baseline (726.726 us; speedup 1.0000x reference)
//
#include <hip/hip_runtime.h>
#include <math.h>

#define N_FFTC    1023
#define NFREQ     512
#define NBANDS    10
#define NPATH     32768
#define NSURF     16
#define NDIR      128
#define RIR_LEN   96000
#define FILT_LEN  1023
#define TWO_PI_D  6.283185307179586476925286766559

typedef _Float16 f16x8 __attribute__((ext_vector_type(8)));
typedef float    f32x4 __attribute__((ext_vector_type(4)));

#define AS1 __attribute__((address_space(1)))
#define AS3 __attribute__((address_space(3)))
__device__ __forceinline__ void gload16(const void* g, void* l) {
    __builtin_amdgcn_global_load_lds((const AS1 void*)g, (AS3 void*)l, 16, 0, 0);
}

// ---- ws layout (bytes) ----
#define WS_RIR    0UL            // f32 [8][96000]                 3,072,000
#define WS_WT     3072000UL      // f16 [2][1024][1024] hi|lo      4,194,304
#define WS_TWC    7266304UL      // dbl [1023]
#define WS_TWS    7274496UL      // dbl [1023]
#define WS_LOGR   7282688UL      // f32 [16][10]
#define WS_SIGD   7283456UL      // f32 [128][10]
#define WS_GS     7329536UL      // dbl [10][512]
#define WS_GD     7370496UL      // dbl [10][512]
#define WS_TBL    7411456UL      // f32x4 [10][512]  {SI,DI,PST,PDT}   81,920
#define WS_A      7493632UL      // f16 [chunkM][2048] (4KB/path) then f32 filt [chunkM][1024] (4KB/path)

// ---------------- k0a: twiddles (fp64) + log_refl + sig_dir ----------------
__global__ void k0a_tables(const float* __restrict__ sp, const float* __restrict__ dp,
                           double* __restrict__ twc, double* __restrict__ tws,
                           float* __restrict__ logr, float* __restrict__ sigd)
{
    int idx = blockIdx.x * 256 + threadIdx.x;
    if (idx < 1023) {
        double ang = TWO_PI_D * (double)idx / 1023.0;
        twc[idx] = cos(ang);
        tws[idx] = sin(ang);
    } else if (idx >= 1024 && idx < 1024 + NSURF * NBANDS) {
        int i = idx - 1024;
        float s = 1.f / (1.f + expf(-sp[i]));
        logr[i] = logf(s <= 1e-9f ? 1e-9f : s);
    } else if (idx >= 2048 && idx < 2048 + NDIR * NBANDS) {
        int i = idx - 2048;
        sigd[i] = 1.f / (1.f + expf(-dp[i]));
    }
}

// ---------------- k0b: G[f][n] = sum_m c_m cos(2pi m n/N) * I[f][m] ----------------
__global__ void k0b_G(const float* __restrict__ SI, const float* __restrict__ DI,
                      const double* __restrict__ twc,
                      double* __restrict__ Gs, double* __restrict__ Gd)
{
    int idx = blockIdx.x * 256 + threadIdx.x;
    if (idx >= NBANDS * NFREQ) return;
    int f = idx >> 9, n = idx & 511;
    double gs = 0.0, gd = 0.0;
    for (int m = 0; m < NFREQ; ++m) {
        double c = (m == 0) ? 1.0 : 2.0;
        double t = c * twc[(m * n) % 1023];
        gs += t * (double)SI[f * NFREQ + m];
        gd += t * (double)DI[f * NFREQ + m];
    }
    Gs[idx] = gs;
    Gd[idx] = gd;
}

// ---------------- k0c: packed table {SI, DI, PST, PDT}[f][k] ----------------
__global__ void k0c_TBL(const double* __restrict__ tws,
                        const double* __restrict__ Gs, const double* __restrict__ Gd,
                        const float* __restrict__ SI, const float* __restrict__ DI,
                        float4* __restrict__ TBL)
{
    int idx = blockIdx.x * 256 + threadIdx.x;
    if (idx >= NBANDS * NFREQ) return;
    int f = idx >> 9, k = idx & 511;
    double ps = 0.0, pd_ = 0.0;
    for (int n = 1; n < 512; ++n) {
        double s = tws[(k * n) % 1023];
        ps  += s * Gs[f * NFREQ + n];
        pd_ += s * Gd[f * NFREQ + n];
    }
    double sc = -2.0 / 1023.0;
    float4 v;
    v.x = SI[idx];
    v.y = DI[idx];
    v.z = (float)(sc * ps);
    v.w = (float)(sc * pd_);
    TBL[idx] = v;
}

// ---------------- k0d: WT[t][k] synthesis matrix (transposed), f16 limbs, x2^14 ----------------
__global__ void k0d_W(const double* __restrict__ twc, const double* __restrict__ tws,
                      _Float16* __restrict__ WThi, _Float16* __restrict__ WTlo)
{
    int idx = blockIdx.x * 256 + threadIdx.x;   // 1024*1024 over [t][k]
    int t = idx >> 10, k = idx & 1023;
    double v = 0.0;
    if (t < 1023) {
        if (k < 512) v = (((k == 0) ? 1.0 : 2.0) / 1023.0) * twc[(k * t) % 1023];
        else         v = (2.0 / 1023.0) * tws[((k - 512) * t) % 1023];
    }
    float vf = (float)(v * 16384.0);
    _Float16 h = (_Float16)vf;
    WThi[idx] = h;
    WTlo[idx] = (_Float16)(vf - (float)h);
}

__device__ __forceinline__ float wave_sum64(float v) {
#pragma unroll
    for (int m = 1; m < 64; m <<= 1) v += __shfl_xor(v, m, 64);
    return v;
}
__device__ __forceinline__ float wave_max64(float v) {
#pragma unroll
    for (int m = 1; m < 64; m <<= 1) v = fmaxf(v, __shfl_xor(v, m, 64));
    return v;
}

// ---------------- k1: per-path a,b limbs; packed table + fast math ----------------
__global__ __launch_bounds__(256) void k1_ab(
    const float* __restrict__ path_dirs, const float* __restrict__ fib,
    const int* __restrict__ mask, const int* __restrict__ delays,
    const float* __restrict__ logr, const float* __restrict__ sigd,
    const float4* __restrict__ TBL,
    _Float16* __restrict__ A, int chunkStart, int m)
{
    __shared__ _Float16 stg[4][2048];
    int wave = threadIdx.x >> 6, lane = threadIdx.x & 63;
    int p = blockIdx.x * 4 + wave;
    if (p >= m) return;
    int pg = chunkStart + p;

    float dx = path_dirs[pg * 3 + 0], dy = path_dirs[pg * 3 + 1], dz = path_dirs[pg * 3 + 2];
    float inv = 1.f / (sqrtf(dx * dx + dy * dy + dz * dz) + 1e-9f);
    dx *= inv; dy *= inv; dz *= inv;

    int n0 = lane, n1 = lane + 64;
    float l0 = 8.f * (dx * fib[n0 * 3] + dy * fib[n0 * 3 + 1] + dz * fib[n0 * 3 + 2]);
    float l1 = 8.f * (dx * fib[n1 * 3] + dy * fib[n1 * 3 + 1] + dz * fib[n1 * 3 + 2]);
    float mx = wave_max64(fmaxf(l0, l1));
    float e0 = __expf(l0 - mx), e1 = __expf(l1 - mx);
    float ssum = wave_sum64(e0 + e1);
    float w0 = e0 / ssum, w1 = e1 / ssum;

    float lad[10];
#pragma unroll
    for (int f = 0; f < NBANDS; ++f) {
        float part = w0 * sigd[n0 * NBANDS + f] + w1 * sigd[n1 * NBANDS + f];
        part = wave_sum64(part);
        lad[f] = __logf(part <= 1e-9f ? 1e-9f : part);
    }

    float las[10];
#pragma unroll
    for (int f = 0; f < NBANDS; ++f) las[f] = 0.f;
    const int* mrow = mask + (size_t)pg * NSURF;
#pragma unroll
    for (int s = 0; s < NSURF; ++s) {
        float mv = (float)mrow[s];
#pragma unroll
        for (int f = 0; f < NBANDS; ++f) las[f] += mv * logr[s * NBANDS + f];
    }

    int dly = delays[pg];
    float g = 1.f / fmaxf((float)dly / 48.f, 1.f);
    float gsc = g * 16384.f;   // fold 2^14 MFMA-denorm-guard scale

#pragma unroll
    for (int i = 0; i < 8; ++i) {
        int q = i * 64 + lane;
        float la = 0.f, ph = 0.f;
#pragma unroll
        for (int f = 0; f < NBANDS; ++f) {
            float4 t4 = TBL[f * NFREQ + q];
            la += las[f] * t4.x + lad[f] * t4.y;
            ph += las[f] * t4.z + lad[f] * t4.w;
        }
        float M = gsc * __expf(la);
        float sn, cs;
        __sincosf(ph, &sn, &cs);
        float av = M * cs, bv = M * sn;
        _Float16 ah = (_Float16)av, bh = (_Float16)bv;
        stg[wave][q]        = ah;
        stg[wave][512 + q]  = bh;
        stg[wave][1024 + q] = (_Float16)(av - (float)ah);
        stg[wave][1536 + q] = (_Float16)(bv - (float)bh);
    }

    // coalesced writeout: 4 x 16B per lane (1KB per wave-instr)
    _Float16* row = A + (size_t)p * 2048;
#pragma unroll
    for (int seg = 0; seg < 4; ++seg) {
        f16x8 v = *(const f16x8*)&stg[wave][seg * 512 + lane * 8];
        *(f16x8*)(row + seg * 512 + lane * 8) = v;
    }
}

// ---------------- k2: pure f16 MFMA GEMM [m x 3072-limb-K] * WT -> filt (dense) ----------------
// C = Ahi*Whi + Alo*Whi + Ahi*Wlo  (panels 0,1,2), descale 2^-28 at store.
#define KSTEPS 96
__global__ __launch_bounds__(256) void k2_gemm(
    const _Float16* __restrict__ A, const _Float16* __restrict__ WT,
    float* __restrict__ filt)
{
    __shared__ __align__(16) char smem[16384];   // As 8KB | Bs 8KB  ([128 rows][32 f16])
    char* Asm = smem;
    char* Bsm = smem + 8192;

    int nwg = gridDim.x, cpx = nwg >> 3, bid = blockIdx.x;
    int swz = (bid & 7) * cpx + (bid >> 3);       // XCD-aware (grid % 8 == 0)
    int rowTile = swz >> 3, colTile = swz & 7;
    int p0 = rowTile * 128, t0 = colTile * 128;

    int tid = threadIdx.x, lane = tid & 63, wid = tid >> 6;
    int wr = wid >> 1, wc = wid & 1;

    f32x4 acc[4][4];
#pragma unroll
    for (int i = 0; i < 4; ++i)
#pragma unroll
        for (int j = 0; j < 4; ++j) acc[i][j] = (f32x4){0.f, 0.f, 0.f, 0.f};

    int d0 = tid * 16;                       // linear staging dest byte (it=0)
    char* ldsA0 = Asm + (tid & ~63) * 16;    // wave-uniform LDS base (+lane*16 implicit)
    char* ldsB0 = Bsm + (tid & ~63) * 16;
    int li = lane & 15, ksl = lane >> 4;
    int sws = (((li >> 1) & 3) ^ ksl) << 4;  // swizzled k-slot byte offset for fragment reads

    for (int ks = 0; ks < KSTEPS; ++ks) {
        int panel = ks >> 5;
        int kk = (ks & 31) * 32;
        int aoff = ((panel == 1) ? 1024 : 0) + kk;
        const _Float16* wbase = WT + ((panel == 2) ? (1 << 20) : 0);
#pragma unroll
        for (int it = 0; it < 2; ++it) {
            int d = d0 + it * 4096;
            int row = d >> 6;
            int inner = (d & 63) ^ (((d >> 7) & 3) << 4);   // pre-swizzled source slot
            const char* gA = (const char*)(A + (size_t)(p0 + row) * 2048 + aoff) + inner;
            const char* gB = (const char*)(wbase + (size_t)(t0 + row) * 1024 + kk) + inner;
            gload16(gA, ldsA0 + it * 4096);
            gload16(gB, ldsB0 + it * 4096);
        }
        __syncthreads();   // vmcnt(0) drained before barrier -> tiles ready

        f16x8 af[4], bf[4];
#pragma unroll
        for (int mm = 0; mm < 4; ++mm)
            af[mm] = *(const f16x8*)(Asm + (wr * 64 + mm * 16 + li) * 64 + sws);
#pragma unroll
        for (int nn = 0; nn < 4; ++nn)
            bf[nn] = *(const f16x8*)(Bsm + (wc * 64 + nn * 16 + li) * 64 + sws);
#pragma unroll
        for (int mm = 0; mm < 4; ++mm)
#pragma unroll
            for (int nn = 0; nn < 4; ++nn)
                acc[mm][nn] = __builtin_amdgcn_mfma_f32_16x16x32_f16(af[mm], bf[nn], acc[mm][nn], 0, 0, 0);
        __syncthreads();   // protect LDS before next stage
    }

    const float dsc = 1.f / (16384.f * 16384.f);  // exact 2^-28
#pragma unroll
    for (int mm = 0; mm < 4; ++mm) {
        int prow = p0 + wr * 64 + mm * 16 + ksl * 4;
#pragma unroll
        for (int r = 0; r < 4; ++r) {
            float* fp = filt + (size_t)(prow + r) * 1024 + t0 + wc * 64 + li;
#pragma unroll
            for (int nn = 0; nn < 4; ++nn)
                fp[nn * 16] = acc[mm][nn][r] * dsc;
        }
    }
}

// ---------------- k4: binned scatter filt -> rir (LDS window, few atomics) ----------------
#define BS    1024
#define NBINS 93
__global__ __launch_bounds__(256) void k4_scatter(
    const float* __restrict__ filt, const int* __restrict__ delays,
    float* __restrict__ rir, int chunkStart, int m)
{
    __shared__ float win[BS + FILT_LEN];   // 2047 f32
    __shared__ int lst[320];
    __shared__ int cnt;
    int b = blockIdx.y, bin = blockIdx.x;
    int binStart = bin * BS;
    for (int i = threadIdx.x; i < BS + FILT_LEN; i += 256) win[i] = 0.f;
    if (threadIdx.x == 0) cnt = 0;
    __syncthreads();

    int lo = b * 4096, hi = lo + 4096;
    if (lo < chunkStart) lo = chunkStart;
    if (hi > chunkStart + m) hi = chunkStart + m;
    for (int p = lo + threadIdx.x; p < hi; p += 256) {
        int d = delays[p];
        if (d >= binStart && d < binStart + BS) {
            int i = atomicAdd(&cnt, 1);
            if (i < 320) lst[i] = p;
        }
    }
    __syncthreads();

    int n = cnt < 320 ? cnt : 320;
    for (int j = 0; j < n; ++j) {
        int p = lst[j];
        int off = delays[p] - binStart;
        const float* fr = filt + (size_t)(p - chunkStart) * 1024;
        for (int i = threadIdx.x; i < FILT_LEN; i += 256)
            win[off + i] += fr[i];
        __syncthreads();   // j-loop lockstep: no RMW races across waves
    }

    float* rb = rir + (size_t)b * RIR_LEN + binStart;
    for (int i = threadIdx.x; i < BS + FILT_LEN; i += 256) {
        float v = win[i];
        if (v != 0.f) atomicAdd(&rb[i], v);
    }
}

// ---------------- k3: 'same' cross-correlation; 8 out/thread, skewed LDS ----------------
#define SEG 2048
#define SK(i) ((i) + ((i) >> 5))
__global__ __launch_bounds__(256) void k3_conv(
    const float* __restrict__ rir, const float* __restrict__ kern, float* __restrict__ out)
{
    __shared__ float rs[3184];     // skewed: logical 2048+1022+8
    __shared__ float ks[FILT_LEN];
    int b = blockIdx.y;
    int t0 = blockIdx.x * SEG;
    for (int i = threadIdx.x; i < FILT_LEN; i += 256) ks[i] = kern[i];
    for (int i = threadIdx.x; i < SEG + FILT_LEN - 1 + 8; i += 256) {
        int t = t0 - 511 + i;
        rs[SK(i)] = (t >= 0 && t < RIR_LEN) ? rir[(size_t)b * RIR_LEN + t] : 0.f;
    }
    __syncthreads();

    int base = threadIdx.x * 8;
    float a0 = 0.f, a1 = 0.f, a2 = 0.f, a3 = 0.f, a4 = 0.f, a5 = 0.f, a6 = 0.f, a7 = 0.f;
    float w0 = rs[SK(base + 0)], w1 = rs[SK(base + 1)], w2 = rs[SK(base + 2)], w3 = rs[SK(base + 3)];
    float w4 = rs[SK(base + 4)], w5 = rs[SK(base + 5)], w6 = rs[SK(base + 6)], w7 = rs[SK(base + 7)];
#pragma unroll 8
    for (int k = 0; k < FILT_LEN; ++k) {
        float kv = ks[k];
        a0 = fmaf(kv, w0, a0); a1 = fmaf(kv, w1, a1);
        a2 = fmaf(kv, w2, a2); a3 = fmaf(kv, w3, a3);
        a4 = fmaf(kv, w4, a4); a5 = fmaf(kv, w5, a5);
        a6 = fmaf(kv, w6, a6); a7 = fmaf(kv, w7, a7);
        w0 = w1; w1 = w2; w2 = w3; w3 = w4; w4 = w5; w5 = w6; w6 = w7;
        w7 = rs[SK(base + k + 8)];
    }
    int t = t0 + base;
    size_t ob = (size_t)b * RIR_LEN;
    if (t + 7 < RIR_LEN) {
        float4 v0 = {a0, a1, a2, a3}, v1 = {a4, a5, a6, a7};
        *(float4*)&out[ob + t]     = v0;
        *(float4*)&out[ob + t + 4] = v1;
    } else {
        float av[8] = {a0, a1, a2, a3, a4, a5, a6, a7};
        for (int j = 0; j < 8; ++j)
            if (t + j < RIR_LEN) out[ob + t + j] = av[j];
    }
}

extern "C" void kernel_launch(void* const* d_in, const int* in_sizes, int n_in,
                              void* d_out, int out_size, void* d_ws, size_t ws_size,
                              hipStream_t stream)
{
    const float* surface_params = (const float*)d_in[0];
    const float* dir_params     = (const float*)d_in[1];
    const float* path_dirs      = (const float*)d_in[2];
    const float* source_kernel  = (const float*)d_in[3];
    const float* surf_interp    = (const float*)d_in[4];
    const float* dir_interp     = (const float*)d_in[5];
    const float* fib_points     = (const float*)d_in[6];
    const int*   mask           = (const int*)d_in[7];
    const int*   delays         = (const int*)d_in[8];
    float* out = (float*)d_out;
    char*  ws  = (char*)d_ws;

    float*     rir  = (float*)(ws + WS_RIR);
    _Float16*  WT   = (_Float16*)(ws + WS_WT);       // [0]=hi, [1<<20]=lo
    double*    twc  = (double*)(ws + WS_TWC);
    double*    tws  = (double*)(ws + WS_TWS);
    float*     logr = (float*)(ws + WS_LOGR);
    float*     sigd = (float*)(ws + WS_SIGD);
    double*    Gs   = (double*)(ws + WS_GS);
    double*    Gd   = (double*)(ws + WS_GD);
    float4*    TBL  = (float4*)(ws + WS_TBL);
    _Float16*  A    = (_Float16*)(ws + WS_A);

    // adaptive chunking: 8KB per path (A 4KB + filt 4KB)
    size_t abCap = (ws_size > WS_A) ? (ws_size - WS_A) : 0;
    long long cm = (long long)((abCap / 8192) & ~(size_t)127);
    if (cm > NPATH) cm = NPATH;
    if (cm < 128)   cm = 128;
    int chunkM = (int)cm;
    float* filt = (float*)(ws + WS_A + (size_t)chunkM * 4096);

    hipMemsetAsync(rir, 0, (size_t)8 * RIR_LEN * sizeof(float), stream);

    k0a_tables<<<16, 256, 0, stream>>>(surface_params, dir_params, twc, tws, logr, sigd);
    k0b_G     <<<20, 256, 0, stream>>>(surf_interp, dir_interp, twc, Gs, Gd);
    k0c_TBL   <<<20, 256, 0, stream>>>(tws, Gs, Gd, surf_interp, dir_interp, TBL);
    k0d_W     <<<4096, 256, 0, stream>>>(twc, tws, WT, WT + (1 << 20));

    for (int cs = 0; cs < NPATH; cs += chunkM) {
        int m = NPATH - cs;
        if (m > chunkM) m = chunkM;
        k1_ab<<<m / 4, 256, 0, stream>>>(path_dirs, fib_points, mask, delays,
                                         logr, sigd, TBL, A, cs, m);
        k2_gemm<<<(m / 128) * 8, 256, 0, stream>>>(A, WT, filt);
        dim3 g4(NBINS, 8);
        k4_scatter<<<g4, 256, 0, stream>>>(filt, delays, rir, cs, m);
    }

    dim3 g3((RIR_LEN + SEG - 1) / SEG, 8);
    k3_conv<<<g3, 256, 0, stream>>>(rir, source_kernel, out);
}

// Round 6
// 643.325 us; speedup vs baseline: 1.1296x; 1.1296x over previous
//
#include <hip/hip_runtime.h>
#include <math.h>

#define N_FFTC    1023
#define NFREQ     512
#define NBANDS    10
#define NPATH     32768
#define NSURF     16
#define NDIR      128
#define RIR_LEN   96000
#define FILT_LEN  1023
#define TWO_PI_D  6.283185307179586476925286766559

typedef _Float16 f16x8 __attribute__((ext_vector_type(8)));
typedef float    f32x4 __attribute__((ext_vector_type(4)));

#define AS1 __attribute__((address_space(1)))
#define AS3 __attribute__((address_space(3)))
__device__ __forceinline__ void gload16(const void* g, void* l) {
    __builtin_amdgcn_global_load_lds((const AS1 void*)g, (AS3 void*)l, 16, 0, 0);
}

// ---- ws layout (bytes) ----
#define WS_RIR    0UL            // f32 [8][96000]                 3,072,000
#define WS_WT     3072000UL      // f16 [2][1024][1024] hi|lo      4,194,304
#define WS_TWC    7266304UL      // dbl [1023]
#define WS_TWS    7274496UL      // dbl [1023]
#define WS_LOGR   7282688UL      // f32 [16][10]
#define WS_SIGD   7283456UL      // f32 [128][10]
#define WS_GS     7329536UL      // dbl [10][512]
#define WS_GD     7370496UL      // dbl [10][512]
#define WS_TBL    7411456UL      // f32x4 [10][512]  {SI,DI,PST,PDT}   81,920
#define WS_A      7493632UL      // f16 [chunkM][2048] (4KB/path) then f32 filt [chunkM][1024] (4KB/path)

// ---------------- k0a: twiddles (fp64) + log_refl + sig_dir ----------------
__global__ void k0a_tables(const float* __restrict__ sp, const float* __restrict__ dp,
                           double* __restrict__ twc, double* __restrict__ tws,
                           float* __restrict__ logr, float* __restrict__ sigd)
{
    int idx = blockIdx.x * 256 + threadIdx.x;
    if (idx < 1023) {
        double ang = TWO_PI_D * (double)idx / 1023.0;
        twc[idx] = cos(ang);
        tws[idx] = sin(ang);
    } else if (idx >= 1024 && idx < 1024 + NSURF * NBANDS) {
        int i = idx - 1024;
        float s = 1.f / (1.f + expf(-sp[i]));
        logr[i] = logf(s <= 1e-9f ? 1e-9f : s);
    } else if (idx >= 2048 && idx < 2048 + NDIR * NBANDS) {
        int i = idx - 2048;
        sigd[i] = 1.f / (1.f + expf(-dp[i]));
    }
}

// ---------------- k0b: G[f][n] = sum_m c_m cos(2pi m n/N) * I[f][m] ----------------
__global__ void k0b_G(const float* __restrict__ SI, const float* __restrict__ DI,
                      const double* __restrict__ twc,
                      double* __restrict__ Gs, double* __restrict__ Gd)
{
    int idx = blockIdx.x * 256 + threadIdx.x;
    if (idx >= NBANDS * NFREQ) return;
    int f = idx >> 9, n = idx & 511;
    double gs = 0.0, gd = 0.0;
    for (int m = 0; m < NFREQ; ++m) {
        double c = (m == 0) ? 1.0 : 2.0;
        double t = c * twc[(m * n) % 1023];
        gs += t * (double)SI[f * NFREQ + m];
        gd += t * (double)DI[f * NFREQ + m];
    }
    Gs[idx] = gs;
    Gd[idx] = gd;
}

// ---------------- k0c: packed table {SI, DI, PST, PDT}[f][k] ----------------
__global__ void k0c_TBL(const double* __restrict__ tws,
                        const double* __restrict__ Gs, const double* __restrict__ Gd,
                        const float* __restrict__ SI, const float* __restrict__ DI,
                        float4* __restrict__ TBL)
{
    int idx = blockIdx.x * 256 + threadIdx.x;
    if (idx >= NBANDS * NFREQ) return;
    int f = idx >> 9, k = idx & 511;
    double ps = 0.0, pd_ = 0.0;
    for (int n = 1; n < 512; ++n) {
        double s = tws[(k * n) % 1023];
        ps  += s * Gs[f * NFREQ + n];
        pd_ += s * Gd[f * NFREQ + n];
    }
    double sc = -2.0 / 1023.0;
    float4 v;
    v.x = SI[idx];
    v.y = DI[idx];
    v.z = (float)(sc * ps);
    v.w = (float)(sc * pd_);
    TBL[idx] = v;
}

// ---------------- k0d: WT[t][k] synthesis matrix (transposed), f16 limbs, x2^14 ----------------
__global__ void k0d_W(const double* __restrict__ twc, const double* __restrict__ tws,
                      _Float16* __restrict__ WThi, _Float16* __restrict__ WTlo)
{
    int idx = blockIdx.x * 256 + threadIdx.x;   // 1024*1024 over [t][k]
    int t = idx >> 10, k = idx & 1023;
    double v = 0.0;
    if (t < 1023) {
        if (k < 512) v = (((k == 0) ? 1.0 : 2.0) / 1023.0) * twc[(k * t) % 1023];
        else         v = (2.0 / 1023.0) * tws[((k - 512) * t) % 1023];
    }
    float vf = (float)(v * 16384.0);
    _Float16 h = (_Float16)vf;
    WThi[idx] = h;
    WTlo[idx] = (_Float16)(vf - (float)h);
}

__device__ __forceinline__ float wave_sum64(float v) {
#pragma unroll
    for (int m = 1; m < 64; m <<= 1) v += __shfl_xor(v, m, 64);
    return v;
}
__device__ __forceinline__ float wave_max64(float v) {
#pragma unroll
    for (int m = 1; m < 64; m <<= 1) v = fmaxf(v, __shfl_xor(v, m, 64));
    return v;
}

// ---------------- k1: per-path a,b limbs; packed table + fast math ----------------
__global__ __launch_bounds__(256) void k1_ab(
    const float* __restrict__ path_dirs, const float* __restrict__ fib,
    const int* __restrict__ mask, const int* __restrict__ delays,
    const float* __restrict__ logr, const float* __restrict__ sigd,
    const float4* __restrict__ TBL,
    _Float16* __restrict__ A, int chunkStart, int m)
{
    __shared__ _Float16 stg[4][2048];
    int wave = threadIdx.x >> 6, lane = threadIdx.x & 63;
    int p = blockIdx.x * 4 + wave;
    if (p >= m) return;
    int pg = chunkStart + p;

    float dx = path_dirs[pg * 3 + 0], dy = path_dirs[pg * 3 + 1], dz = path_dirs[pg * 3 + 2];
    float inv = 1.f / (sqrtf(dx * dx + dy * dy + dz * dz) + 1e-9f);
    dx *= inv; dy *= inv; dz *= inv;

    int n0 = lane, n1 = lane + 64;
    float l0 = 8.f * (dx * fib[n0 * 3] + dy * fib[n0 * 3 + 1] + dz * fib[n0 * 3 + 2]);
    float l1 = 8.f * (dx * fib[n1 * 3] + dy * fib[n1 * 3 + 1] + dz * fib[n1 * 3 + 2]);
    float mx = wave_max64(fmaxf(l0, l1));
    float e0 = __expf(l0 - mx), e1 = __expf(l1 - mx);
    float ssum = wave_sum64(e0 + e1);
    float w0 = e0 / ssum, w1 = e1 / ssum;

    float lad[10];
#pragma unroll
    for (int f = 0; f < NBANDS; ++f) {
        float part = w0 * sigd[n0 * NBANDS + f] + w1 * sigd[n1 * NBANDS + f];
        part = wave_sum64(part);
        lad[f] = __logf(part <= 1e-9f ? 1e-9f : part);
    }

    float las[10];
#pragma unroll
    for (int f = 0; f < NBANDS; ++f) las[f] = 0.f;
    const int* mrow = mask + (size_t)pg * NSURF;
#pragma unroll
    for (int s = 0; s < NSURF; ++s) {
        float mv = (float)mrow[s];
#pragma unroll
        for (int f = 0; f < NBANDS; ++f) las[f] += mv * logr[s * NBANDS + f];
    }

    int dly = delays[pg];
    float g = 1.f / fmaxf((float)dly / 48.f, 1.f);
    float gsc = g * 16384.f;   // fold 2^14 MFMA-denorm-guard scale

#pragma unroll
    for (int i = 0; i < 8; ++i) {
        int q = i * 64 + lane;
        float la = 0.f, ph = 0.f;
#pragma unroll
        for (int f = 0; f < NBANDS; ++f) {
            float4 t4 = TBL[f * NFREQ + q];
            la += las[f] * t4.x + lad[f] * t4.y;
            ph += las[f] * t4.z + lad[f] * t4.w;
        }
        float M = gsc * __expf(la);
        float sn, cs;
        __sincosf(ph, &sn, &cs);
        float av = M * cs, bv = M * sn;
        _Float16 ah = (_Float16)av, bh = (_Float16)bv;
        stg[wave][q]        = ah;
        stg[wave][512 + q]  = bh;
        stg[wave][1024 + q] = (_Float16)(av - (float)ah);
        stg[wave][1536 + q] = (_Float16)(bv - (float)bh);
    }

    // coalesced writeout: 4 x 16B per lane (1KB per wave-instr)
    _Float16* row = A + (size_t)p * 2048;
#pragma unroll
    for (int seg = 0; seg < 4; ++seg) {
        f16x8 v = *(const f16x8*)&stg[wave][seg * 512 + lane * 8];
        *(f16x8*)(row + seg * 512 + lane * 8) = v;
    }
}

// ---------------- k2: pure f16 MFMA GEMM [m x 3072-limb-K] * WT -> filt (dense) ----------------
// C = Ahi*Whi + Alo*Whi + Ahi*Wlo  (panels 0,1,2), descale 2^-28 at store.
#define KSTEPS 96
__global__ __launch_bounds__(256) void k2_gemm(
    const _Float16* __restrict__ A, const _Float16* __restrict__ WT,
    float* __restrict__ filt)
{
    __shared__ __align__(16) char smem[16384];   // As 8KB | Bs 8KB  ([128 rows][32 f16])
    char* Asm = smem;
    char* Bsm = smem + 8192;

    int nwg = gridDim.x, cpx = nwg >> 3, bid = blockIdx.x;
    int swz = (bid & 7) * cpx + (bid >> 3);       // XCD-aware (grid % 8 == 0)
    int rowTile = swz >> 3, colTile = swz & 7;
    int p0 = rowTile * 128, t0 = colTile * 128;

    int tid = threadIdx.x, lane = tid & 63, wid = tid >> 6;
    int wr = wid >> 1, wc = wid & 1;

    f32x4 acc[4][4];
#pragma unroll
    for (int i = 0; i < 4; ++i)
#pragma unroll
        for (int j = 0; j < 4; ++j) acc[i][j] = (f32x4){0.f, 0.f, 0.f, 0.f};

    int d0 = tid * 16;                       // linear staging dest byte (it=0)
    char* ldsA0 = Asm + (tid & ~63) * 16;    // wave-uniform LDS base (+lane*16 implicit)
    char* ldsB0 = Bsm + (tid & ~63) * 16;
    int li = lane & 15, ksl = lane >> 4;
    int sws = (((li >> 1) & 3) ^ ksl) << 4;  // swizzled k-slot byte offset for fragment reads

    for (int ks = 0; ks < KSTEPS; ++ks) {
        int panel = ks >> 5;
        int kk = (ks & 31) * 32;
        int aoff = ((panel == 1) ? 1024 : 0) + kk;
        const _Float16* wbase = WT + ((panel == 2) ? (1 << 20) : 0);
#pragma unroll
        for (int it = 0; it < 2; ++it) {
            int d = d0 + it * 4096;
            int row = d >> 6;
            int inner = (d & 63) ^ (((d >> 7) & 3) << 4);   // pre-swizzled source slot
            const char* gA = (const char*)(A + (size_t)(p0 + row) * 2048 + aoff) + inner;
            const char* gB = (const char*)(wbase + (size_t)(t0 + row) * 1024 + kk) + inner;
            gload16(gA, ldsA0 + it * 4096);
            gload16(gB, ldsB0 + it * 4096);
        }
        __syncthreads();   // vmcnt(0) drained before barrier -> tiles ready

        f16x8 af[4], bf[4];
#pragma unroll
        for (int mm = 0; mm < 4; ++mm)
            af[mm] = *(const f16x8*)(Asm + (wr * 64 + mm * 16 + li) * 64 + sws);
#pragma unroll
        for (int nn = 0; nn < 4; ++nn)
            bf[nn] = *(const f16x8*)(Bsm + (wc * 64 + nn * 16 + li) * 64 + sws);
#pragma unroll
        for (int mm = 0; mm < 4; ++mm)
#pragma unroll
            for (int nn = 0; nn < 4; ++nn)
                acc[mm][nn] = __builtin_amdgcn_mfma_f32_16x16x32_f16(af[mm], bf[nn], acc[mm][nn], 0, 0, 0);
        __syncthreads();   // protect LDS before next stage
    }

    const float dsc = 1.f / (16384.f * 16384.f);  // exact 2^-28
#pragma unroll
    for (int mm = 0; mm < 4; ++mm) {
        int prow = p0 + wr * 64 + mm * 16 + ksl * 4;
#pragma unroll
        for (int r = 0; r < 4; ++r) {
            float* fp = filt + (size_t)(prow + r) * 1024 + t0 + wc * 64 + li;
#pragma unroll
            for (int nn = 0; nn < 4; ++nn)
                fp[nn * 16] = acc[mm][nn][r] * dsc;
        }
    }
}

// ---------------- k4: binned scatter filt -> rir; per-wave windows, barrier-free ----------------
// A 1024-f32 row is 4KB = FOUR wave-wide float4 loads (not one!): seg 0..3, lane covers
// elements seg*256 + lane*4 .. +3.  filt[p][1023]==0 by construction (W col 1023 zero).
#define BS    1024
#define NBINS 93
__global__ __launch_bounds__(256) void k4_scatter(
    const float* __restrict__ filt, const int* __restrict__ delays,
    float* __restrict__ rir, int chunkStart, int m)
{
    __shared__ float win4[4][2048];    // per-wave private window (32KB)
    int b = blockIdx.y, bin = blockIdx.x;
    int binStart = bin * BS;
    int wid = threadIdx.x >> 6, lane = threadIdx.x & 63;

    for (int i = lane; i < 2048; i += 64) win4[wid][i] = 0.f;  // own window only -> no barrier

    int lo = b * 4096, hi = lo + 4096;
    if (lo < chunkStart) lo = chunkStart;
    if (hi > chunkStart + m) hi = chunkStart + m;

    // wave-interleaved scan; ballot + bit-iterate matches; no barriers -> loads pipeline
    for (int base = lo + wid * 64; base < hi; base += 256) {
        int p = base + lane;
        int d = (p < hi) ? delays[p] : -1;
        bool match = (d >= binStart) && (d < binStart + BS);
        unsigned long long mask = __ballot(match);
        while (mask) {
            int bit = __ffsll(mask) - 1;
            mask &= mask - 1;
            int ps = base + bit;
            int off = __shfl(d, bit) - binStart;
            const float4* fr = (const float4*)(filt + (size_t)(ps - chunkStart) * 1024);
            float4 v0 = fr[lane];
            float4 v1 = fr[64 + lane];
            float4 v2 = fr[128 + lane];
            float4 v3 = fr[192 + lane];
            float* w0 = &win4[wid][off + lane * 4];
            w0[0] += v0.x; w0[1] += v0.y; w0[2] += v0.z; w0[3] += v0.w;
            float* w1 = w0 + 256;
            w1[0] += v1.x; w1[1] += v1.y; w1[2] += v1.z; w1[3] += v1.w;
            float* w2 = w0 + 512;
            w2[0] += v2.x; w2[1] += v2.y; w2[2] += v2.z; w2[3] += v2.w;
            float* w3 = w0 + 768;
            w3[0] += v3.x; w3[1] += v3.y; w3[2] += v3.z; w3[3] += v3.w;
        }
    }
    __syncthreads();

    int imax = RIR_LEN - binStart; if (imax > 2047) imax = 2047;
    float* rb = rir + (size_t)b * RIR_LEN + binStart;
    for (int i = threadIdx.x; i < imax; i += 256) {
        float v = win4[0][i] + win4[1][i] + win4[2][i] + win4[3][i];
        if (v != 0.f) atomicAdd(&rb[i], v);
    }
}

// ---------------- k3: 'same' cross-correlation; 8 out/thread, skewed LDS ----------------
#define SEG 2048
#define SK(i) ((i) + ((i) >> 5))
__global__ __launch_bounds__(256) void k3_conv(
    const float* __restrict__ rir, const float* __restrict__ kern, float* __restrict__ out)
{
    __shared__ float rs[3184];     // skewed: logical 2048+1022+8
    __shared__ float ks[FILT_LEN];
    int b = blockIdx.y;
    int t0 = blockIdx.x * SEG;
    for (int i = threadIdx.x; i < FILT_LEN; i += 256) ks[i] = kern[i];
    for (int i = threadIdx.x; i < SEG + FILT_LEN - 1 + 8; i += 256) {
        int t = t0 - 511 + i;
        rs[SK(i)] = (t >= 0 && t < RIR_LEN) ? rir[(size_t)b * RIR_LEN + t] : 0.f;
    }
    __syncthreads();

    int base = threadIdx.x * 8;
    float a0 = 0.f, a1 = 0.f, a2 = 0.f, a3 = 0.f, a4 = 0.f, a5 = 0.f, a6 = 0.f, a7 = 0.f;
    float w0 = rs[SK(base + 0)], w1 = rs[SK(base + 1)], w2 = rs[SK(base + 2)], w3 = rs[SK(base + 3)];
    float w4 = rs[SK(base + 4)], w5 = rs[SK(base + 5)], w6 = rs[SK(base + 6)], w7 = rs[SK(base + 7)];
#pragma unroll 8
    for (int k = 0; k < FILT_LEN; ++k) {
        float kv = ks[k];
        a0 = fmaf(kv, w0, a0); a1 = fmaf(kv, w1, a1);
        a2 = fmaf(kv, w2, a2); a3 = fmaf(kv, w3, a3);
        a4 = fmaf(kv, w4, a4); a5 = fmaf(kv, w5, a5);
        a6 = fmaf(kv, w6, a6); a7 = fmaf(kv, w7, a7);
        w0 = w1; w1 = w2; w2 = w3; w3 = w4; w4 = w5; w5 = w6; w6 = w7;
        w7 = rs[SK(base + k + 8)];
    }
    int t = t0 + base;
    size_t ob = (size_t)b * RIR_LEN;
    if (t + 7 < RIR_LEN) {
        float4 v0 = {a0, a1, a2, a3}, v1 = {a4, a5, a6, a7};
        *(float4*)&out[ob + t]     = v0;
        *(float4*)&out[ob + t + 4] = v1;
    } else {
        float av[8] = {a0, a1, a2, a3, a4, a5, a6, a7};
        for (int j = 0; j < 8; ++j)
            if (t + j < RIR_LEN) out[ob + t + j] = av[j];
    }
}

extern "C" void kernel_launch(void* const* d_in, const int* in_sizes, int n_in,
                              void* d_out, int out_size, void* d_ws, size_t ws_size,
                              hipStream_t stream)
{
    const float* surface_params = (const float*)d_in[0];
    const float* dir_params     = (const float*)d_in[1];
    const float* path_dirs      = (const float*)d_in[2];
    const float* source_kernel  = (const float*)d_in[3];
    const float* surf_interp    = (const float*)d_in[4];
    const float* dir_interp     = (const float*)d_in[5];
    const float* fib_points     = (const float*)d_in[6];
    const int*   mask           = (const int*)d_in[7];
    const int*   delays         = (const int*)d_in[8];
    float* out = (float*)d_out;
    char*  ws  = (char*)d_ws;

    float*     rir  = (float*)(ws + WS_RIR);
    _Float16*  WT   = (_Float16*)(ws + WS_WT);       // [0]=hi, [1<<20]=lo
    double*    twc  = (double*)(ws + WS_TWC);
    double*    tws  = (double*)(ws + WS_TWS);
    float*     logr = (float*)(ws + WS_LOGR);
    float*     sigd = (float*)(ws + WS_SIGD);
    double*    Gs   = (double*)(ws + WS_GS);
    double*    Gd   = (double*)(ws + WS_GD);
    float4*    TBL  = (float4*)(ws + WS_TBL);
    _Float16*  A    = (_Float16*)(ws + WS_A);

    // adaptive chunking: 8KB per path (A 4KB + filt 4KB)
    size_t abCap = (ws_size > WS_A) ? (ws_size - WS_A) : 0;
    long long cm = (long long)((abCap / 8192) & ~(size_t)127);
    if (cm > NPATH) cm = NPATH;
    if (cm < 128)   cm = 128;
    int chunkM = (int)cm;
    float* filt = (float*)(ws + WS_A + (size_t)chunkM * 4096);

    hipMemsetAsync(rir, 0, (size_t)8 * RIR_LEN * sizeof(float), stream);

    k0a_tables<<<16, 256, 0, stream>>>(surface_params, dir_params, twc, tws, logr, sigd);
    k0b_G     <<<20, 256, 0, stream>>>(surf_interp, dir_interp, twc, Gs, Gd);
    k0c_TBL   <<<20, 256, 0, stream>>>(tws, Gs, Gd, surf_interp, dir_interp, TBL);
    k0d_W     <<<4096, 256, 0, stream>>>(twc, tws, WT, WT + (1 << 20));

    for (int cs = 0; cs < NPATH; cs += chunkM) {
        int m = NPATH - cs;
        if (m > chunkM) m = chunkM;
        k1_ab<<<m / 4, 256, 0, stream>>>(path_dirs, fib_points, mask, delays,
                                         logr, sigd, TBL, A, cs, m);
        k2_gemm<<<(m / 128) * 8, 256, 0, stream>>>(A, WT, filt);
        dim3 g4(NBINS, 8);
        k4_scatter<<<g4, 256, 0, stream>>>(filt, delays, rir, cs, m);
    }

    dim3 g3((RIR_LEN + SEG - 1) / SEG, 8);
    k3_conv<<<g3, 256, 0, stream>>>(rir, source_kernel, out);
}